// Round 8
// baseline (1340.793 us; speedup 1.0000x reference)
//
#include <hip/hip_runtime.h>

typedef unsigned int u32;
typedef unsigned short u16;

#define NEG 0.01f
#define BN_EPS 1e-5f

typedef __attribute__((ext_vector_type(8))) short bf16x8;
typedef __attribute__((ext_vector_type(4))) float f32x4;

__device__ __forceinline__ float bl(u32 u){ union { u32 i; float f; } c; c.i = u << 16; return c.f; }
__device__ __forceinline__ float bh(u32 u){ union { u32 i; float f; } c; c.i = u & 0xFFFF0000u; return c.f; }
__device__ __forceinline__ u16 f2b(float f){
  union { float f; u32 i; } c; c.f = f;
  u32 t = c.i + 0x7FFFu + ((c.i >> 16) & 1u);
  return (u16)(t >> 16);
}
__device__ __forceinline__ float leaky(float v){ return v > 0.f ? v : NEG * v; }

// ---------------------------------------------------------------------------
// Kernel H: per-(dst,rel) histogram into LINE-PADDED bins (64B per bin) to
// kill same-line atomic serialization (was ~512 atomics/line at 800KB table).
// ---------------------------------------------------------------------------
__global__ __launch_bounds__(256) void k_hist(
    const int* __restrict__ ei, const int* __restrict__ et, int E,
    int* __restrict__ deg2p)
{
  int e = blockIdx.x * 256 + threadIdx.x;
  if (e < E) {
    int bin = ei[E + e] * 2 + et[e];
    atomicAdd(&deg2p[(size_t)bin << 4], 1);
  }
}

// ---------------------------------------------------------------------------
// Kernel P: fused [prep | conv].
//  blocks [0, PB)      : weight prep fp32 -> bf16 tables
//    tab layout: [0,49152)  Wpk fragment-ordered: i = ((k*4+t)*64+lane)*8+j
//                           = desW[16t+(lane&15)][32k+8*(lane>>4)+j]
//                [49152,57344) Wmlp[64][128] row h: {rgcnW0[h][:], rgcnW1[h][:]}
//                [57344,59392) W1p[32][64]
//  blocks [PB, PB+NB)  : des fp32 -> bf16 fragment-ordered pack, with
//    COALESCED row-major reads (wave = contiguous 2KB) and scattered 16B
//    writes confined to the block's own 96KB output (L2-merged).
//    des16[fb*49152 + ((w*24+k)*64 + q*16 + l15)*8 + j]
//      = f2b(des[fb*64 + 16w + l15][32k + 8q + j])     (row clamped)
// ---------------------------------------------------------------------------
__global__ __launch_bounds__(256) void k_prep_conv(
    int PB,
    const float* __restrict__ desWf, const float* __restrict__ rgcnW,
    const float* __restrict__ W1, u16* __restrict__ tab,
    const float* __restrict__ des, u16* __restrict__ des16, int n)
{
  int bid = blockIdx.x;
  if (bid < PB) {
    int i = bid * 256 + threadIdx.x;
    if (i < 49152) {
      int j = i & 7, lane = (i >> 3) & 63, t = (i >> 9) & 3, k = i >> 11;
      int row = 16 * t + (lane & 15);
      int col = 32 * k + 8 * (lane >> 4) + j;
      tab[i] = f2b(desWf[row * 768 + col]);
    } else if (i < 57344) {
      int j = i - 49152;            // h*128 + k
      int h = j >> 7, k = j & 127;
      tab[i] = f2b(rgcnW[(k >= 64 ? 4096 : 0) + h * 64 + (k & 63)]);
    } else if (i < 59392) {
      tab[i] = f2b(W1[i - 57344]);
    }
  } else {
    int fb = bid - PB;
    const int tid = threadIdx.x;
    u16* outb = des16 + (size_t)fb * 49152;
    #pragma unroll 4
    for (int it = 0; it < 24; ++it) {
      int g = it * 256 + tid;                 // 0..6143 row-major 8-float slot
      int r      = g / 96;                    // row in block 0..63
      int colblk = g - r * 96;                // 8-float block 0..95
      int row = fb * 64 + r;
      if (row > n - 1) row = n - 1;
      const float* p = des + (size_t)row * 768 + colblk * 8;
      float4 u = *(const float4*)p;
      float4 v = *(const float4*)(p + 4);
      int4 o4;
      o4.x = (int)((u32)f2b(u.x) | ((u32)f2b(u.y) << 16));
      o4.y = (int)((u32)f2b(u.z) | ((u32)f2b(u.w) << 16));
      o4.z = (int)((u32)f2b(v.x) | ((u32)f2b(v.y) << 16));
      o4.w = (int)((u32)f2b(v.z) | ((u32)f2b(v.w) << 16));
      // fragment-order destination slot
      int w  = r >> 4, l15 = r & 15;
      int k  = colblk >> 2, q = colblk & 3;
      int s  = (w * 24 + k) * 64 + q * 16 + l15;
      *(int4*)(outb + (size_t)s * 8) = o4;
    }
  }
}

// ---------------------------------------------------------------------------
// Kernel B: fused [scan | fuse-GEMM].
//  block 0       : exclusive prefix sum over M=2N padded bins
//  blocks [1, ..]: fusion GEMM via MFMA -> x16[node][64] bf16.
//  Both A (des16) and B (Wpk) are fragment-ordered: every hot-loop load is
//  a contiguous 1KB wave-load (lane*16B). No conversion VALU in the loop.
// ---------------------------------------------------------------------------
__global__ __launch_bounds__(256) void k_fuse_scan(
    const u16* __restrict__ des16, const float* __restrict__ nump, const float* __restrict__ catp,
    const u16* __restrict__ Wpk, const float* __restrict__ desB,
    const float* __restrict__ numW, const float* __restrict__ numB,
    const float* __restrict__ catW, const float* __restrict__ catB,
    const float* __restrict__ dg, const float* __restrict__ dbe, const float* __restrict__ dm, const float* __restrict__ dv,
    const float* __restrict__ ng, const float* __restrict__ nbe, const float* __restrict__ nm, const float* __restrict__ nv,
    const float* __restrict__ cg, const float* __restrict__ cbe, const float* __restrict__ cm, const float* __restrict__ cv,
    u16* __restrict__ x16, int n,
    const int* __restrict__ deg2p, int* __restrict__ offs2, int M)
{
  const int tid  = threadIdx.x;
  const int lane = tid & 63;
  const int w    = tid >> 6;

  if (blockIdx.x == 0) {
    // ---- 256-thread exclusive scan over M padded bins (M % 4 == 0) ----
    __shared__ int wsum[4];
    __shared__ int carry;
    if (tid == 0) carry = 0;
    __syncthreads();
    for (int base = 0; base < M; base += 1024) {
      int idx = base + tid * 4;
      int4 v = {0, 0, 0, 0};
      if (idx < M) {
        v.x = deg2p[(size_t)(idx + 0) << 4];
        v.y = deg2p[(size_t)(idx + 1) << 4];
        v.z = deg2p[(size_t)(idx + 2) << 4];
        v.w = deg2p[(size_t)(idx + 3) << 4];
      }
      int s4 = v.x + v.y + v.z + v.w;
      int s = s4;
      #pragma unroll
      for (int o = 1; o < 64; o <<= 1) { int t = __shfl_up(s, o); if (lane >= o) s += t; }
      if (lane == 63) wsum[w] = s;
      __syncthreads();
      if (tid == 0) {
        int a = wsum[0];
        a += wsum[1]; wsum[1] = a;
        a += wsum[2]; wsum[2] = a;
        a += wsum[3]; wsum[3] = a;
      }
      __syncthreads();
      int wbase = (w == 0) ? 0 : wsum[w - 1];
      int ebase = carry + wbase + (s - s4);
      if (idx < M) {
        int4 o4;
        o4.x = ebase;
        o4.y = ebase + v.x;
        o4.z = ebase + v.x + v.y;
        o4.w = ebase + v.x + v.y + v.z;
        *(int4*)(offs2 + idx) = o4;
      }
      __syncthreads();
      if (tid == 0) carry += wsum[3];
      __syncthreads();
    }
    if (tid == 0) offs2[M] = carry;
    return;
  }

  // ---- fusion GEMM (blocks 1..) ----
  __shared__ float ync[64][66];

  const int quad = lane >> 4;
  const int l15  = lane & 15;
  const int fb   = blockIdx.x - 1;
  const int rowbase = fb * 64 + 16 * w;

  {
    float nw[5], cw[6];
    #pragma unroll
    for (int j = 0; j < 5; ++j) nw[j] = numW[lane * 5 + j];
    #pragma unroll
    for (int j = 0; j < 6; ++j) cw[j] = catW[lane * 6 + j];
    float An = ng[lane] * rsqrtf(nv[lane] + BN_EPS);
    float Bn = (numB[lane] - nm[lane]) * An + nbe[lane];
    float Ac = cg[lane] * rsqrtf(cv[lane] + BN_EPS);
    float Bc = (catB[lane] - cm[lane]) * Ac + cbe[lane];
    for (int m = 0; m < 16; ++m) {
      int node = rowbase + m; if (node > n - 1) node = n - 1;
      float yn = 0.f, yc = 0.f;
      #pragma unroll
      for (int j = 0; j < 5; ++j) yn = fmaf(nump[node * 5 + j], nw[j], yn);
      #pragma unroll
      for (int j = 0; j < 6; ++j) yc = fmaf(catp[node * 6 + j], cw[j], yc);
      ync[16 * w + m][lane] = leaky(yn * An + Bn) + leaky(yc * Ac + Bc);
    }
  }

  float Ad4[4], Bd4[4];
  #pragma unroll
  for (int t = 0; t < 4; ++t) {
    int nn = 16 * t + l15;
    float A = dg[nn] * rsqrtf(dv[nn] + BN_EPS);
    Ad4[t] = A;
    Bd4[t] = (desB[nn] - dm[nn]) * A + dbe[nn];
  }
  __syncthreads();

  // fragment-ordered operands: contiguous 16B per lane
  const u16* aP = des16 + (size_t)(fb * 4 + w) * 12288 + lane * 8;  // + k*512
  const u16* bP = Wpk + lane * 8;                                   // + k*2048 + t*512

  f32x4 acc[4];
  #pragma unroll
  for (int t = 0; t < 4; ++t) acc[t] = (f32x4){0.f, 0.f, 0.f, 0.f};

  #pragma unroll 4
  for (int k = 0; k < 24; ++k) {
    bf16x8 a = *(const bf16x8*)(aP + k * 512);
    acc[0] = __builtin_amdgcn_mfma_f32_16x16x32_bf16(a, *(const bf16x8*)(bP + k * 2048       ), acc[0], 0, 0, 0);
    acc[1] = __builtin_amdgcn_mfma_f32_16x16x32_bf16(a, *(const bf16x8*)(bP + k * 2048 +  512), acc[1], 0, 0, 0);
    acc[2] = __builtin_amdgcn_mfma_f32_16x16x32_bf16(a, *(const bf16x8*)(bP + k * 2048 + 1024), acc[2], 0, 0, 0);
    acc[3] = __builtin_amdgcn_mfma_f32_16x16x32_bf16(a, *(const bf16x8*)(bP + k * 2048 + 1536), acc[3], 0, 0, 0);
  }

  #pragma unroll
  for (int t = 0; t < 4; ++t) {
    #pragma unroll
    for (int r = 0; r < 4; ++r) {
      int m = quad * 4 + r;
      int node = rowbase + m;
      if (node < n) {
        int nn = 16 * t + l15;
        float v = leaky(acc[t][r] * Ad4[t] + Bd4[t]) + ync[16 * w + m][nn];
        x16[(size_t)node * 64 + nn] = f2b(v);
      }
    }
  }
}

// ---------------------------------------------------------------------------
// Kernel C: CSR placement sorted by (dst, rel). packed[pos] = src.
// cur2p is line-padded like deg2p.
// ---------------------------------------------------------------------------
__global__ void k_place(const int* __restrict__ ei, const int* __restrict__ et, int E,
                        const int* __restrict__ offs2, int* __restrict__ cur2p, int* __restrict__ packed)
{
  int e = blockIdx.x * 256 + threadIdx.x;
  if (e < E) {
    int bin = ei[E + e] * 2 + et[e];
    int pos = offs2[bin] + atomicAdd(&cur2p[(size_t)bin << 4], 1);
    packed[pos] = ei[e];
  }
}

// ---------------------------------------------------------------------------
// Kernel D: pure gather/mean. Wave per node; lane = channel-pair (c=lane&31),
// half-wave = edge substream -> one u32 wave-load gathers TWO edges' rows.
// ---------------------------------------------------------------------------
__global__ __launch_bounds__(256) void k_agg(
    const u16* __restrict__ x16, const int* __restrict__ offs2, const int* __restrict__ packed,
    u32* __restrict__ agg, int n)
{
  const int tid = threadIdx.x, lane = tid & 63, w = tid >> 6;
  const int c = lane & 31, half = lane >> 5;

  for (int nd = blockIdx.x * 4 + w; nd < n; nd += gridDim.x * 4) {
    int o0 = offs2[nd * 2], o1 = offs2[nd * 2 + 1], o2 = offs2[nd * 2 + 2];
    float aE[2], aO[2];

    #pragma unroll
    for (int rel = 0; rel < 2; ++rel) {
      int beg = rel ? o1 : o0;
      int end = rel ? o2 : o1;
      float accE = 0.f, accO = 0.f;
      for (int j0 = beg; j0 < end; j0 += 64) {
        int idx = j0 + lane;
        int p = (idx < end) ? packed[idx] : 0;
        p = (p < 0) ? 0 : ((p > n - 1) ? (n - 1) : p);
        int cn = end - j0; if (cn > 64) cn = 64;
        int t = 0;
        for (; t + 16 <= cn; t += 16) {        // 16 edges: 8 dual-edge loads in flight
          int s0 = __shfl(p, t      + half);
          int s1 = __shfl(p, t + 2  + half);
          int s2 = __shfl(p, t + 4  + half);
          int s3 = __shfl(p, t + 6  + half);
          int s4 = __shfl(p, t + 8  + half);
          int s5 = __shfl(p, t + 10 + half);
          int s6 = __shfl(p, t + 12 + half);
          int s7 = __shfl(p, t + 14 + half);
          u32 v0 = *(const u32*)(x16 + (size_t)s0 * 64 + 2 * c);
          u32 v1 = *(const u32*)(x16 + (size_t)s1 * 64 + 2 * c);
          u32 v2 = *(const u32*)(x16 + (size_t)s2 * 64 + 2 * c);
          u32 v3 = *(const u32*)(x16 + (size_t)s3 * 64 + 2 * c);
          u32 v4 = *(const u32*)(x16 + (size_t)s4 * 64 + 2 * c);
          u32 v5 = *(const u32*)(x16 + (size_t)s5 * 64 + 2 * c);
          u32 v6 = *(const u32*)(x16 + (size_t)s6 * 64 + 2 * c);
          u32 v7 = *(const u32*)(x16 + (size_t)s7 * 64 + 2 * c);
          accE += ((bl(v0) + bl(v1)) + (bl(v2) + bl(v3))) + ((bl(v4) + bl(v5)) + (bl(v6) + bl(v7)));
          accO += ((bh(v0) + bh(v1)) + (bh(v2) + bh(v3))) + ((bh(v4) + bh(v5)) + (bh(v6) + bh(v7)));
        }
        for (; t + 8 <= cn; t += 8) {          // 8 edges: 4 dual-edge loads
          int s0 = __shfl(p, t     + half);
          int s1 = __shfl(p, t + 2 + half);
          int s2 = __shfl(p, t + 4 + half);
          int s3 = __shfl(p, t + 6 + half);
          u32 v0 = *(const u32*)(x16 + (size_t)s0 * 64 + 2 * c);
          u32 v1 = *(const u32*)(x16 + (size_t)s1 * 64 + 2 * c);
          u32 v2 = *(const u32*)(x16 + (size_t)s2 * 64 + 2 * c);
          u32 v3 = *(const u32*)(x16 + (size_t)s3 * 64 + 2 * c);
          accE += (bl(v0) + bl(v1)) + (bl(v2) + bl(v3));
          accO += (bh(v0) + bh(v1)) + (bh(v2) + bh(v3));
        }
        for (; t + 2 <= cn; t += 2) {          // 2 edges per load
          int s0 = __shfl(p, t + half);
          u32 v0 = *(const u32*)(x16 + (size_t)s0 * 64 + 2 * c);
          accE += bl(v0); accO += bh(v0);
        }
        if (t < cn) {                           // odd remainder: half 0 only
          int s0 = __shfl(p, t);
          if (half == 0) {
            u32 v0 = *(const u32*)(x16 + (size_t)s0 * 64 + 2 * c);
            accE += bl(v0); accO += bh(v0);
          }
        }
      }
      accE += __shfl_xor(accE, 32);
      accO += __shfl_xor(accO, 32);
      int cnt = end - beg;
      float sc = 1.f / (float)(cnt > 1 ? cnt : 1);
      aE[rel] = accE * sc;
      aO[rel] = accO * sc;
    }

    float sE = half ? aE[1] : aE[0];
    float sO = half ? aO[1] : aO[0];
    agg[(size_t)nd * 64 + lane] = (u32)f2b(sE) | ((u32)f2b(sO) << 16);
  }
}

// ---------------------------------------------------------------------------
// Kernel E: batched MFMA MLP.  A = agg[node][128] bf16.
// y64 = leaky(0.5 * A @ Wmlp^T); h32 = leaky(y64 @ W1p^T + b1);
// out2 = h32 @ W2^T + b2.   64 nodes/block (4 waves x 16).
// ---------------------------------------------------------------------------
__global__ __launch_bounds__(256) void k_mlp(
    const u32* __restrict__ agg, const u16* __restrict__ Wmlp, const u16* __restrict__ W1p,
    const float* __restrict__ b1, const float* __restrict__ W2, const float* __restrict__ b2,
    float2* __restrict__ out, int n)
{
  __shared__ __align__(16) u16 h1[4][16][72];   // [wave][node m][ch 0..63], 16B-aligned rows
  __shared__ float h2[4][16][34];               // [wave][node m][j 0..31]

  const int tid = threadIdx.x, lane = tid & 63, w = tid >> 6;
  const int quad = lane >> 4, l15 = lane & 15;
  const int rowbase = blockIdx.x * 64 + 16 * w;

  int rowA = rowbase + l15; if (rowA > n - 1) rowA = n - 1;
  const u16* aRow = (const u16*)(agg + (size_t)rowA * 64);   // 128 bf16

  // ---- GEMM1: [16 nodes x 128] @ [128 -> 64] ----
  f32x4 acc[4];
  #pragma unroll
  for (int t = 0; t < 4; ++t) acc[t] = (f32x4){0.f, 0.f, 0.f, 0.f};
  #pragma unroll
  for (int ks = 0; ks < 4; ++ks) {
    bf16x8 a = *(const bf16x8*)(aRow + ks * 32 + quad * 8);
    #pragma unroll
    for (int t = 0; t < 4; ++t) {
      bf16x8 b = *(const bf16x8*)(Wmlp + (size_t)(16 * t + l15) * 128 + ks * 32 + quad * 8);
      acc[t] = __builtin_amdgcn_mfma_f32_16x16x32_bf16(a, b, acc[t], 0, 0, 0);
    }
  }
  #pragma unroll
  for (int t = 0; t < 4; ++t)
    #pragma unroll
    for (int r = 0; r < 4; ++r) {
      int m = quad * 4 + r;
      h1[w][m][16 * t + l15] = f2b(leaky(0.5f * acc[t][r]));
    }
  __syncthreads();

  // ---- GEMM2: [16 x 64] @ [64 -> 32] ----
  f32x4 acc2[2];
  acc2[0] = (f32x4){0.f, 0.f, 0.f, 0.f};
  acc2[1] = (f32x4){0.f, 0.f, 0.f, 0.f};
  #pragma unroll
  for (int ks = 0; ks < 2; ++ks) {
    bf16x8 a = *(const bf16x8*)(&h1[w][l15][ks * 32 + quad * 8]);
    #pragma unroll
    for (int t = 0; t < 2; ++t) {
      bf16x8 b = *(const bf16x8*)(W1p + (size_t)(16 * t + l15) * 64 + ks * 32 + quad * 8);
      acc2[t] = __builtin_amdgcn_mfma_f32_16x16x32_bf16(a, b, acc2[t], 0, 0, 0);
    }
  }
  #pragma unroll
  for (int t = 0; t < 2; ++t)
    #pragma unroll
    for (int r = 0; r < 4; ++r) {
      int m = quad * 4 + r;
      int j = 16 * t + l15;
      h2[w][m][j] = leaky(acc2[t][r] + b1[j]);
    }
  __syncthreads();

  // ---- final 32 -> 2: lane (quad,l15): node l15, j-range quad*8..+8 ----
  float t0 = 0.f, t1 = 0.f;
  #pragma unroll
  for (int jj = 0; jj < 8; ++jj) {
    int j = quad * 8 + jj;
    float hv = h2[w][l15][j];
    t0 = fmaf(hv, W2[j], t0);
    t1 = fmaf(hv, W2[32 + j], t1);
  }
  t0 += __shfl_xor(t0, 16); t0 += __shfl_xor(t0, 32);
  t1 += __shfl_xor(t1, 16); t1 += __shfl_xor(t1, 32);
  int node = rowbase + l15;
  if (quad == 0 && node < n) {
    float2 q; q.x = t0 + b2[0]; q.y = t1 + b2[1];
    out[node] = q;
  }
}

// ---------------------------------------------------------------------------
extern "C" void kernel_launch(void* const* d_in, const int* in_sizes, int n_in,
                              void* d_out, int out_size, void* d_ws, size_t ws_size,
                              hipStream_t stream)
{
  const float* des  = (const float*)d_in[0];
  const float* nump = (const float*)d_in[1];
  const float* catp = (const float*)d_in[2];
  const int* ei   = (const int*)d_in[3];
  const int* et   = (const int*)d_in[4];
  const float* desW = (const float*)d_in[5];
  const float* desB = (const float*)d_in[6];
  const float* numW = (const float*)d_in[7];
  const float* numB = (const float*)d_in[8];
  const float* catW = (const float*)d_in[9];
  const float* catB = (const float*)d_in[10];
  const float* dg  = (const float*)d_in[11];
  const float* dbe = (const float*)d_in[12];
  const float* dm  = (const float*)d_in[13];
  const float* dv  = (const float*)d_in[14];
  const float* ng  = (const float*)d_in[15];
  const float* nbe = (const float*)d_in[16];
  const float* nm  = (const float*)d_in[17];
  const float* nv  = (const float*)d_in[18];
  const float* cg  = (const float*)d_in[19];
  const float* cbe = (const float*)d_in[20];
  const float* cm  = (const float*)d_in[21];
  const float* cv  = (const float*)d_in[22];
  const float* rgcnW = (const float*)d_in[23];
  const float* W1 = (const float*)d_in[24];
  const float* b1 = (const float*)d_in[25];
  const float* W2 = (const float*)d_in[26];
  const float* b2 = (const float*)d_in[27];

  const int N = in_sizes[1] / 5;   // num is (N,5)
  const int E = in_sizes[4];       // edge_type is (E,)
  const int M = 2 * N;             // (dst, rel) bins
  const int NB = (N + 63) / 64;    // node blocks (64 rows each)

  // workspace layout
  char* ws = (char*)d_ws;
  u16* tab    = (u16*)ws;                  size_t off = (size_t)59392 * 2;      // weight tables
  off = (off + 255) & ~(size_t)255;
  u16* x16    = (u16*)(ws + off);          off += (size_t)N * 64 * 2;
  u32* agg    = (u32*)(ws + off);          off += (size_t)N * 64 * 4;
  int* deg2p  = (int*)(ws + off);          off += (size_t)M * 64;   // line-padded bins
  int* cur2p  = (int*)(ws + off);          off += (size_t)M * 64;   // line-padded bins
  int* offs2  = (int*)(ws + off);          off += (size_t)(M + 1) * 4;
  off = (off + 255) & ~(size_t)255;
  int* packed = (int*)(ws + off);          off += (size_t)E * 4;
  off = (off + 255) & ~(size_t)255;
  u16* des16  = (u16*)(ws + off);          // NB * 49152 u16 (~150 MB)

  u16* Wpk    = tab;
  u16* Wmlp   = tab + 49152;
  u16* W1p    = tab + 57344;

  hipMemsetAsync(deg2p, 0, (size_t)M * 128, stream);  // zero deg2p + cur2p (adjacent)

  const int HB = (E + 255) / 256;
  const int PB = (59392 + 255) / 256;

  k_hist<<<HB, 256, 0, stream>>>(ei, et, E, deg2p);
  k_prep_conv<<<PB + NB, 256, 0, stream>>>(PB, desW, rgcnW, W1, tab, des, des16, N);

  k_fuse_scan<<<NB + 1, 256, 0, stream>>>(des16, nump, catp, Wpk, desB, numW, numB, catW, catB,
                                          dg, dbe, dm, dv, ng, nbe, nm, nv, cg, cbe, cm, cv,
                                          x16, N, deg2p, offs2, M);

  k_place<<<(E + 255) / 256, 256, 0, stream>>>(ei, et, E, offs2, cur2p, packed);
  k_agg<<<2048, 256, 0, stream>>>(x16, offs2, packed, agg, N);
  k_mlp<<<(N + 63) / 64, 256, 0, stream>>>(agg, Wmlp, W1p, b1, W2, b2, (float2*)d_out, N);
}

// Round 9
// 941.974 us; speedup vs baseline: 1.4234x; 1.4234x over previous
//
#include <hip/hip_runtime.h>

typedef unsigned int u32;
typedef unsigned short u16;

#define NEG 0.01f
#define BN_EPS 1e-5f

typedef __attribute__((ext_vector_type(8))) short bf16x8;
typedef __attribute__((ext_vector_type(4))) float f32x4;

__device__ __forceinline__ float bl(u32 u){ union { u32 i; float f; } c; c.i = u << 16; return c.f; }
__device__ __forceinline__ float bh(u32 u){ union { u32 i; float f; } c; c.i = u & 0xFFFF0000u; return c.f; }
__device__ __forceinline__ u16 f2b(float f){
  union { float f; u32 i; } c; c.f = f;
  u32 t = c.i + 0x7FFFu + ((c.i >> 16) & 1u);
  return (u16)(t >> 16);
}
__device__ __forceinline__ float leaky(float v){ return v > 0.f ? v : NEG * v; }

// ---------------------------------------------------------------------------
// Kernel A: fused [hist | prep], DENSE bins (padding reverted: R8 showed the
// line-padded bins made the single-block scan latency-bound, +180us tail).
//  blocks [0, HB)      : per-(dst,rel) histogram, bin = dst*2 + rel
//  blocks [HB, HB+PB)  : weight prep fp32 -> bf16 tables
//    tab layout: [0,49152)  Wpk fragment-ordered: i = ((k*4+t)*64+lane)*8+j
//                           = desW[16t+(lane&15)][32k+8*(lane>>4)+j]
//                [49152,57344) Wmlp[64][128] row h: {rgcnW0[h][:], rgcnW1[h][:]}
//                [57344,59392) W1p[32][64]
// ---------------------------------------------------------------------------
__global__ __launch_bounds__(256) void k_hist_prep(
    const int* __restrict__ ei, const int* __restrict__ et, int E, int HB,
    int* __restrict__ deg2,
    const float* __restrict__ desWf, const float* __restrict__ rgcnW,
    const float* __restrict__ W1, u16* __restrict__ tab)
{
  int bid = blockIdx.x;
  if (bid < HB) {
    int e = bid * 256 + threadIdx.x;
    if (e < E) atomicAdd(&deg2[ei[E + e] * 2 + et[e]], 1);
  } else {
    int i = (bid - HB) * 256 + threadIdx.x;
    if (i < 49152) {
      int j = i & 7, lane = (i >> 3) & 63, t = (i >> 9) & 3, k = i >> 11;
      int row = 16 * t + (lane & 15);
      int col = 32 * k + 8 * (lane >> 4) + j;
      tab[i] = f2b(desWf[row * 768 + col]);
    } else if (i < 57344) {
      int j = i - 49152;            // h*128 + k
      int h = j >> 7, k = j & 127;
      tab[i] = f2b(rgcnW[(k >= 64 ? 4096 : 0) + h * 64 + (k & 63)]);
    } else if (i < 59392) {
      tab[i] = f2b(W1[i - 57344]);
    }
  }
}

// ---------------------------------------------------------------------------
// Kernel B: fused [scan | fuse-GEMM], LDS-staged, reads des DIRECTLY
// (des16 intermediate + conv pass eliminated: was a redundant ~460MB round
// trip). Staging: coalesced 512B row-segment loads -> fp32->bf16 pack ->
// LDS tile [64][136] (16B-aligned rows) -> per-lane b128 fragment reads.
// HBM floor ~55-80us; LDS/MFMA cycles are ~5x below the HBM cost.
//  block 0       : exclusive prefix sum over M=2N DENSE bins (R7 code)
//  blocks [1, ..]: fusion GEMM -> x16[node][64] bf16
// ---------------------------------------------------------------------------
__global__ __launch_bounds__(256) void k_fuse_scan(
    const float* __restrict__ des, const float* __restrict__ nump, const float* __restrict__ catp,
    const u16* __restrict__ Wpk, const float* __restrict__ desB,
    const float* __restrict__ numW, const float* __restrict__ numB,
    const float* __restrict__ catW, const float* __restrict__ catB,
    const float* __restrict__ dg, const float* __restrict__ dbe, const float* __restrict__ dm, const float* __restrict__ dv,
    const float* __restrict__ ng, const float* __restrict__ nbe, const float* __restrict__ nm, const float* __restrict__ nv,
    const float* __restrict__ cg, const float* __restrict__ cbe, const float* __restrict__ cm, const float* __restrict__ cv,
    u16* __restrict__ x16, int n,
    const int* __restrict__ deg2, int* __restrict__ offs2, int M)
{
  const int tid  = threadIdx.x;
  const int lane = tid & 63;
  const int w    = tid >> 6;

  if (blockIdx.x == 0) {
    // ---- 256-thread exclusive scan over M dense bins (M % 4 == 0) ----
    __shared__ int wsum[4];
    __shared__ int carry;
    if (tid == 0) carry = 0;
    __syncthreads();
    for (int base = 0; base < M; base += 1024) {
      int idx = base + tid * 4;
      int4 v = {0, 0, 0, 0};
      if (idx < M) v = *(const int4*)(deg2 + idx);
      int s4 = v.x + v.y + v.z + v.w;
      int s = s4;
      #pragma unroll
      for (int o = 1; o < 64; o <<= 1) { int t = __shfl_up(s, o); if (lane >= o) s += t; }
      if (lane == 63) wsum[w] = s;
      __syncthreads();
      if (tid == 0) {
        int a = wsum[0];
        a += wsum[1]; wsum[1] = a;
        a += wsum[2]; wsum[2] = a;
        a += wsum[3]; wsum[3] = a;
      }
      __syncthreads();
      int wbase = (w == 0) ? 0 : wsum[w - 1];
      int ebase = carry + wbase + (s - s4);
      if (idx < M) {
        int4 o4;
        o4.x = ebase;
        o4.y = ebase + v.x;
        o4.z = ebase + v.x + v.y;
        o4.w = ebase + v.x + v.y + v.z;
        *(int4*)(offs2 + idx) = o4;
      }
      __syncthreads();
      if (tid == 0) carry += wsum[3];
      __syncthreads();
    }
    if (tid == 0) offs2[M] = carry;
    return;
  }

  // ---- fusion GEMM (blocks 1..) ----
  __shared__ float ync[64][66];                 // 16896 B
  __shared__ __align__(16) u16 atile[64 * 136]; // 17408 B, row stride 136 bf16 (16B-aligned)

  const int quad = lane >> 4;
  const int l15  = lane & 15;
  const int fb   = blockIdx.x - 1;
  const int rowbase = fb * 64 + 16 * w;

  {
    float nw[5], cw[6];
    #pragma unroll
    for (int j = 0; j < 5; ++j) nw[j] = numW[lane * 5 + j];
    #pragma unroll
    for (int j = 0; j < 6; ++j) cw[j] = catW[lane * 6 + j];
    float An = ng[lane] * rsqrtf(nv[lane] + BN_EPS);
    float Bn = (numB[lane] - nm[lane]) * An + nbe[lane];
    float Ac = cg[lane] * rsqrtf(cv[lane] + BN_EPS);
    float Bc = (catB[lane] - cm[lane]) * Ac + cbe[lane];
    for (int m = 0; m < 16; ++m) {
      int node = rowbase + m; if (node > n - 1) node = n - 1;
      float yn = 0.f, yc = 0.f;
      #pragma unroll
      for (int j = 0; j < 5; ++j) yn = fmaf(nump[node * 5 + j], nw[j], yn);
      #pragma unroll
      for (int j = 0; j < 6; ++j) yc = fmaf(catp[node * 6 + j], cw[j], yc);
      ync[16 * w + m][lane] = leaky(yn * An + Bn) + leaky(yc * Ac + Bc);
    }
  }

  float Ad4[4], Bd4[4];
  #pragma unroll
  for (int t = 0; t < 4; ++t) {
    int nn = 16 * t + l15;
    float A = dg[nn] * rsqrtf(dv[nn] + BN_EPS);
    Ad4[t] = A;
    Bd4[t] = (desB[nn] - dm[nn]) * A + dbe[nn];
  }
  __syncthreads();

  const u16* bP = Wpk + lane * 8;     // + kg*2048 + t*512, contiguous 1KB/wave

  f32x4 acc[4];
  #pragma unroll
  for (int t = 0; t < 4; ++t) acc[t] = (f32x4){0.f, 0.f, 0.f, 0.f};

  const int blk64 = fb * 64;
  for (int tile = 0; tile < 6; ++tile) {
    if (tile > 0) __syncthreads();   // all waves done reading previous tile
    // ---- stage 64 rows x 128 cols (fp32 -> bf16), coalesced 512B segments ----
    #pragma unroll
    for (int it = 0; it < 4; ++it) {
      int j  = it * 256 + tid;        // 0..1023
      int r  = j >> 4;                // row-in-block 0..63
      int sg = j & 15;                // 8-float segment 0..15
      int row = blk64 + r; if (row > n - 1) row = n - 1;
      const float* p = des + (size_t)row * 768 + tile * 128 + sg * 8;
      float4 u = *(const float4*)p;
      float4 v = *(const float4*)(p + 4);
      u32* d = (u32*)(atile + r * 136 + sg * 8);
      d[0] = (u32)f2b(u.x) | ((u32)f2b(u.y) << 16);
      d[1] = (u32)f2b(u.z) | ((u32)f2b(u.w) << 16);
      d[2] = (u32)f2b(v.x) | ((u32)f2b(v.y) << 16);
      d[3] = (u32)f2b(v.z) | ((u32)f2b(v.w) << 16);
    }
    __syncthreads();
    // ---- 4 K-steps of MFMA from LDS fragments ----
    #pragma unroll
    for (int kk = 0; kk < 4; ++kk) {
      bf16x8 a = *(const bf16x8*)(atile + (16 * w + l15) * 136 + kk * 32 + quad * 8);
      int kg = tile * 4 + kk;         // global K-step 0..23
      acc[0] = __builtin_amdgcn_mfma_f32_16x16x32_bf16(a, *(const bf16x8*)(bP + kg * 2048       ), acc[0], 0, 0, 0);
      acc[1] = __builtin_amdgcn_mfma_f32_16x16x32_bf16(a, *(const bf16x8*)(bP + kg * 2048 +  512), acc[1], 0, 0, 0);
      acc[2] = __builtin_amdgcn_mfma_f32_16x16x32_bf16(a, *(const bf16x8*)(bP + kg * 2048 + 1024), acc[2], 0, 0, 0);
      acc[3] = __builtin_amdgcn_mfma_f32_16x16x32_bf16(a, *(const bf16x8*)(bP + kg * 2048 + 1536), acc[3], 0, 0, 0);
    }
  }

  #pragma unroll
  for (int t = 0; t < 4; ++t) {
    #pragma unroll
    for (int r = 0; r < 4; ++r) {
      int m = quad * 4 + r;
      int node = rowbase + m;
      if (node < n) {
        int nn = 16 * t + l15;
        float v = leaky(acc[t][r] * Ad4[t] + Bd4[t]) + ync[16 * w + m][nn];
        x16[(size_t)node * 64 + nn] = f2b(v);
      }
    }
  }
}

// ---------------------------------------------------------------------------
// Kernel C: CSR placement sorted by (dst, rel). packed[pos] = src. Dense cur2.
// ---------------------------------------------------------------------------
__global__ void k_place(const int* __restrict__ ei, const int* __restrict__ et, int E,
                        const int* __restrict__ offs2, int* __restrict__ cur2, int* __restrict__ packed)
{
  int e = blockIdx.x * 256 + threadIdx.x;
  if (e < E) {
    int bin = ei[E + e] * 2 + et[e];
    int pos = offs2[bin] + atomicAdd(&cur2[bin], 1);
    packed[pos] = ei[e];
  }
}

// ---------------------------------------------------------------------------
// Kernel D: pure gather/mean. Wave per node; lane = channel-pair (c=lane&31),
// half-wave = edge substream -> one u32 wave-load gathers TWO edges' rows.
// ---------------------------------------------------------------------------
__global__ __launch_bounds__(256) void k_agg(
    const u16* __restrict__ x16, const int* __restrict__ offs2, const int* __restrict__ packed,
    u32* __restrict__ agg, int n)
{
  const int tid = threadIdx.x, lane = tid & 63, w = tid >> 6;
  const int c = lane & 31, half = lane >> 5;

  for (int nd = blockIdx.x * 4 + w; nd < n; nd += gridDim.x * 4) {
    int o0 = offs2[nd * 2], o1 = offs2[nd * 2 + 1], o2 = offs2[nd * 2 + 2];
    float aE[2], aO[2];

    #pragma unroll
    for (int rel = 0; rel < 2; ++rel) {
      int beg = rel ? o1 : o0;
      int end = rel ? o2 : o1;
      float accE = 0.f, accO = 0.f;
      for (int j0 = beg; j0 < end; j0 += 64) {
        int idx = j0 + lane;
        int p = (idx < end) ? packed[idx] : 0;
        p = (p < 0) ? 0 : ((p > n - 1) ? (n - 1) : p);
        int cn = end - j0; if (cn > 64) cn = 64;
        int t = 0;
        for (; t + 16 <= cn; t += 16) {        // 16 edges: 8 dual-edge loads in flight
          int s0 = __shfl(p, t      + half);
          int s1 = __shfl(p, t + 2  + half);
          int s2 = __shfl(p, t + 4  + half);
          int s3 = __shfl(p, t + 6  + half);
          int s4 = __shfl(p, t + 8  + half);
          int s5 = __shfl(p, t + 10 + half);
          int s6 = __shfl(p, t + 12 + half);
          int s7 = __shfl(p, t + 14 + half);
          u32 v0 = *(const u32*)(x16 + (size_t)s0 * 64 + 2 * c);
          u32 v1 = *(const u32*)(x16 + (size_t)s1 * 64 + 2 * c);
          u32 v2 = *(const u32*)(x16 + (size_t)s2 * 64 + 2 * c);
          u32 v3 = *(const u32*)(x16 + (size_t)s3 * 64 + 2 * c);
          u32 v4 = *(const u32*)(x16 + (size_t)s4 * 64 + 2 * c);
          u32 v5 = *(const u32*)(x16 + (size_t)s5 * 64 + 2 * c);
          u32 v6 = *(const u32*)(x16 + (size_t)s6 * 64 + 2 * c);
          u32 v7 = *(const u32*)(x16 + (size_t)s7 * 64 + 2 * c);
          accE += ((bl(v0) + bl(v1)) + (bl(v2) + bl(v3))) + ((bl(v4) + bl(v5)) + (bl(v6) + bl(v7)));
          accO += ((bh(v0) + bh(v1)) + (bh(v2) + bh(v3))) + ((bh(v4) + bh(v5)) + (bh(v6) + bh(v7)));
        }
        for (; t + 8 <= cn; t += 8) {          // 8 edges: 4 dual-edge loads
          int s0 = __shfl(p, t     + half);
          int s1 = __shfl(p, t + 2 + half);
          int s2 = __shfl(p, t + 4 + half);
          int s3 = __shfl(p, t + 6 + half);
          u32 v0 = *(const u32*)(x16 + (size_t)s0 * 64 + 2 * c);
          u32 v1 = *(const u32*)(x16 + (size_t)s1 * 64 + 2 * c);
          u32 v2 = *(const u32*)(x16 + (size_t)s2 * 64 + 2 * c);
          u32 v3 = *(const u32*)(x16 + (size_t)s3 * 64 + 2 * c);
          accE += (bl(v0) + bl(v1)) + (bl(v2) + bl(v3));
          accO += (bh(v0) + bh(v1)) + (bh(v2) + bh(v3));
        }
        for (; t + 2 <= cn; t += 2) {          // 2 edges per load
          int s0 = __shfl(p, t + half);
          u32 v0 = *(const u32*)(x16 + (size_t)s0 * 64 + 2 * c);
          accE += bl(v0); accO += bh(v0);
        }
        if (t < cn) {                           // odd remainder: half 0 only
          int s0 = __shfl(p, t);
          if (half == 0) {
            u32 v0 = *(const u32*)(x16 + (size_t)s0 * 64 + 2 * c);
            accE += bl(v0); accO += bh(v0);
          }
        }
      }
      accE += __shfl_xor(accE, 32);
      accO += __shfl_xor(accO, 32);
      int cnt = end - beg;
      float sc = 1.f / (float)(cnt > 1 ? cnt : 1);
      aE[rel] = accE * sc;
      aO[rel] = accO * sc;
    }

    float sE = half ? aE[1] : aE[0];
    float sO = half ? aO[1] : aO[0];
    agg[(size_t)nd * 64 + lane] = (u32)f2b(sE) | ((u32)f2b(sO) << 16);
  }
}

// ---------------------------------------------------------------------------
// Kernel E: batched MFMA MLP.  A = agg[node][128] bf16.
// y64 = leaky(0.5 * A @ Wmlp^T); h32 = leaky(y64 @ W1p^T + b1);
// out2 = h32 @ W2^T + b2.   64 nodes/block (4 waves x 16).
// ---------------------------------------------------------------------------
__global__ __launch_bounds__(256) void k_mlp(
    const u32* __restrict__ agg, const u16* __restrict__ Wmlp, const u16* __restrict__ W1p,
    const float* __restrict__ b1, const float* __restrict__ W2, const float* __restrict__ b2,
    float2* __restrict__ out, int n)
{
  __shared__ __align__(16) u16 h1[4][16][72];   // [wave][node m][ch 0..63], 16B-aligned rows
  __shared__ float h2[4][16][34];               // [wave][node m][j 0..31]

  const int tid = threadIdx.x, lane = tid & 63, w = tid >> 6;
  const int quad = lane >> 4, l15 = lane & 15;
  const int rowbase = blockIdx.x * 64 + 16 * w;

  int rowA = rowbase + l15; if (rowA > n - 1) rowA = n - 1;
  const u16* aRow = (const u16*)(agg + (size_t)rowA * 64);   // 128 bf16

  // ---- GEMM1: [16 nodes x 128] @ [128 -> 64] ----
  f32x4 acc[4];
  #pragma unroll
  for (int t = 0; t < 4; ++t) acc[t] = (f32x4){0.f, 0.f, 0.f, 0.f};
  #pragma unroll
  for (int ks = 0; ks < 4; ++ks) {
    bf16x8 a = *(const bf16x8*)(aRow + ks * 32 + quad * 8);
    #pragma unroll
    for (int t = 0; t < 4; ++t) {
      bf16x8 b = *(const bf16x8*)(Wmlp + (size_t)(16 * t + l15) * 128 + ks * 32 + quad * 8);
      acc[t] = __builtin_amdgcn_mfma_f32_16x16x32_bf16(a, b, acc[t], 0, 0, 0);
    }
  }
  #pragma unroll
  for (int t = 0; t < 4; ++t)
    #pragma unroll
    for (int r = 0; r < 4; ++r) {
      int m = quad * 4 + r;
      h1[w][m][16 * t + l15] = f2b(leaky(0.5f * acc[t][r]));
    }
  __syncthreads();

  // ---- GEMM2: [16 x 64] @ [64 -> 32] ----
  f32x4 acc2[2];
  acc2[0] = (f32x4){0.f, 0.f, 0.f, 0.f};
  acc2[1] = (f32x4){0.f, 0.f, 0.f, 0.f};
  #pragma unroll
  for (int ks = 0; ks < 2; ++ks) {
    bf16x8 a = *(const bf16x8*)(&h1[w][l15][ks * 32 + quad * 8]);
    #pragma unroll
    for (int t = 0; t < 2; ++t) {
      bf16x8 b = *(const bf16x8*)(W1p + (size_t)(16 * t + l15) * 64 + ks * 32 + quad * 8);
      acc2[t] = __builtin_amdgcn_mfma_f32_16x16x32_bf16(a, b, acc2[t], 0, 0, 0);
    }
  }
  #pragma unroll
  for (int t = 0; t < 2; ++t)
    #pragma unroll
    for (int r = 0; r < 4; ++r) {
      int m = quad * 4 + r;
      int j = 16 * t + l15;
      h2[w][m][j] = leaky(acc2[t][r] + b1[j]);
    }
  __syncthreads();

  // ---- final 32 -> 2: lane (quad,l15): node l15, j-range quad*8..+8 ----
  float t0 = 0.f, t1 = 0.f;
  #pragma unroll
  for (int jj = 0; jj < 8; ++jj) {
    int j = quad * 8 + jj;
    float hv = h2[w][l15][j];
    t0 = fmaf(hv, W2[j], t0);
    t1 = fmaf(hv, W2[32 + j], t1);
  }
  t0 += __shfl_xor(t0, 16); t0 += __shfl_xor(t0, 32);
  t1 += __shfl_xor(t1, 16); t1 += __shfl_xor(t1, 32);
  int node = rowbase + l15;
  if (quad == 0 && node < n) {
    float2 q; q.x = t0 + b2[0]; q.y = t1 + b2[1];
    out[node] = q;
  }
}

// ---------------------------------------------------------------------------
extern "C" void kernel_launch(void* const* d_in, const int* in_sizes, int n_in,
                              void* d_out, int out_size, void* d_ws, size_t ws_size,
                              hipStream_t stream)
{
  const float* des  = (const float*)d_in[0];
  const float* nump = (const float*)d_in[1];
  const float* catp = (const float*)d_in[2];
  const int* ei   = (const int*)d_in[3];
  const int* et   = (const int*)d_in[4];
  const float* desW = (const float*)d_in[5];
  const float* desB = (const float*)d_in[6];
  const float* numW = (const float*)d_in[7];
  const float* numB = (const float*)d_in[8];
  const float* catW = (const float*)d_in[9];
  const float* catB = (const float*)d_in[10];
  const float* dg  = (const float*)d_in[11];
  const float* dbe = (const float*)d_in[12];
  const float* dm  = (const float*)d_in[13];
  const float* dv  = (const float*)d_in[14];
  const float* ng  = (const float*)d_in[15];
  const float* nbe = (const float*)d_in[16];
  const float* nm  = (const float*)d_in[17];
  const float* nv  = (const float*)d_in[18];
  const float* cg  = (const float*)d_in[19];
  const float* cbe = (const float*)d_in[20];
  const float* cm  = (const float*)d_in[21];
  const float* cv  = (const float*)d_in[22];
  const float* rgcnW = (const float*)d_in[23];
  const float* W1 = (const float*)d_in[24];
  const float* b1 = (const float*)d_in[25];
  const float* W2 = (const float*)d_in[26];
  const float* b2 = (const float*)d_in[27];

  const int N = in_sizes[1] / 5;   // num is (N,5)
  const int E = in_sizes[4];       // edge_type is (E,)
  const int M = 2 * N;             // (dst, rel) bins
  const int NB = (N + 63) / 64;    // node blocks (64 rows each)

  // workspace layout
  char* ws = (char*)d_ws;
  u16* tab    = (u16*)ws;                  size_t off = (size_t)59392 * 2;      // weight tables
  off = (off + 255) & ~(size_t)255;
  u16* x16    = (u16*)(ws + off);          off += (size_t)N * 64 * 2;
  u32* agg    = (u32*)(ws + off);          off += (size_t)N * 64 * 4;
  int* deg2   = (int*)(ws + off);          off += (size_t)M * 4;
  int* cur2   = (int*)(ws + off);          off += (size_t)M * 4;
  int* offs2  = (int*)(ws + off);          off += (size_t)(M + 1) * 4;
  off = (off + 255) & ~(size_t)255;
  int* packed = (int*)(ws + off);

  u16* Wpk    = tab;
  u16* Wmlp   = tab + 49152;
  u16* W1p    = tab + 57344;

  hipMemsetAsync(deg2, 0, (size_t)M * 8, stream);     // zero deg2 + cur2 (adjacent)

  const int HB = (E + 255) / 256;
  const int PB = (59392 + 255) / 256;
  k_hist_prep<<<HB + PB, 256, 0, stream>>>(ei, et, E, HB, deg2, desW, rgcnW, W1, tab);

  k_fuse_scan<<<NB + 1, 256, 0, stream>>>(des, nump, catp, Wpk, desB, numW, numB, catW, catB,
                                          dg, dbe, dm, dv, ng, nbe, nm, nv, cg, cbe, cm, cv,
                                          x16, N, deg2, offs2, M);

  k_place<<<(E + 255) / 256, 256, 0, stream>>>(ei, et, E, offs2, cur2, packed);
  k_agg<<<2048, 256, 0, stream>>>(x16, offs2, packed, agg, N);
  k_mlp<<<(N + 63) / 64, 256, 0, stream>>>(agg, Wmlp, W1p, b1, W2, b2, (float2*)d_out, N);
}

// Round 10
// 872.446 us; speedup vs baseline: 1.5368x; 1.0797x over previous
//
#include <hip/hip_runtime.h>

typedef unsigned int u32;
typedef unsigned short u16;

#define NEG 0.01f
#define BN_EPS 1e-5f

typedef __attribute__((ext_vector_type(8))) short bf16x8;
typedef __attribute__((ext_vector_type(4))) float f32x4;

__device__ __forceinline__ float bl(u32 u){ union { u32 i; float f; } c; c.i = u << 16; return c.f; }
__device__ __forceinline__ float bh(u32 u){ union { u32 i; float f; } c; c.i = u & 0xFFFF0000u; return c.f; }
__device__ __forceinline__ u16 f2b(float f){
  union { float f; u32 i; } c; c.f = f;
  u32 t = c.i + 0x7FFFu + ((c.i >> 16) & 1u);
  return (u16)(t >> 16);
}
__device__ __forceinline__ float leaky(float v){ return v > 0.f ? v : NEG * v; }

// ---------------------------------------------------------------------------
// Kernel A: fused [hist | prep], dense bins.
// ---------------------------------------------------------------------------
__global__ __launch_bounds__(256) void k_hist_prep(
    const int* __restrict__ ei, const int* __restrict__ et, int E, int HB,
    int* __restrict__ deg2,
    const float* __restrict__ desWf, const float* __restrict__ rgcnW,
    const float* __restrict__ W1, u16* __restrict__ tab)
{
  int bid = blockIdx.x;
  if (bid < HB) {
    int e = bid * 256 + threadIdx.x;
    if (e < E) atomicAdd(&deg2[ei[E + e] * 2 + et[e]], 1);
  } else {
    int i = (bid - HB) * 256 + threadIdx.x;
    if (i < 49152) {
      int j = i & 7, lane = (i >> 3) & 63, t = (i >> 9) & 3, k = i >> 11;
      int row = 16 * t + (lane & 15);
      int col = 32 * k + 8 * (lane >> 4) + j;
      tab[i] = f2b(desWf[row * 768 + col]);
    } else if (i < 57344) {
      int j = i - 49152;            // h*128 + k
      int h = j >> 7, k = j & 127;
      tab[i] = f2b(rgcnW[(k >= 64 ? 4096 : 0) + h * 64 + (k & 63)]);
    } else if (i < 59392) {
      tab[i] = f2b(W1[i - 57344]);
    }
  }
}

// ---------------------------------------------------------------------------
// Parallel scan over M bins (was: serial 196-chunk single-block scan = the
// 219us pole in R5/R9; R8's padded variant at 436us confirmed the mechanism).
// Stage A: 1024-bin chunk sums.  Stage B: scan the 196 chunk sums.
// Stage C: local chunk scan + chunk offset -> offs2.
// ---------------------------------------------------------------------------
__global__ __launch_bounds__(256) void k_scanA(
    const int* __restrict__ deg2, int* __restrict__ psum, int M)
{
  __shared__ int ws4[4];
  const int tid = threadIdx.x, lane = tid & 63, w = tid >> 6;
  int idx = blockIdx.x * 1024 + tid * 4;
  int4 v = {0, 0, 0, 0};
  if (idx < M) v = *(const int4*)(deg2 + idx);
  int s = v.x + v.y + v.z + v.w;
  #pragma unroll
  for (int o = 1; o < 64; o <<= 1) s += __shfl_xor(s, o);
  if (lane == 0) ws4[w] = s;
  __syncthreads();
  if (tid == 0) psum[blockIdx.x] = ws4[0] + ws4[1] + ws4[2] + ws4[3];
}

__global__ __launch_bounds__(256) void k_scanB(
    const int* __restrict__ psum, int* __restrict__ poff, int NCH)
{
  __shared__ int wsum[4];
  const int tid = threadIdx.x, lane = tid & 63, w = tid >> 6;
  int v = (tid < NCH) ? psum[tid] : 0;
  int s = v;
  #pragma unroll
  for (int o = 1; o < 64; o <<= 1) { int t = __shfl_up(s, o); if (lane >= o) s += t; }
  if (lane == 63) wsum[w] = s;
  __syncthreads();
  if (tid == 0) {
    int a = wsum[0];
    a += wsum[1]; wsum[1] = a;
    a += wsum[2]; wsum[2] = a;
    a += wsum[3]; wsum[3] = a;
  }
  __syncthreads();
  int wbase = (w == 0) ? 0 : wsum[w - 1];
  if (tid < NCH) poff[tid] = wbase + (s - v);
}

__global__ __launch_bounds__(256) void k_scanC(
    const int* __restrict__ deg2, const int* __restrict__ poff,
    int* __restrict__ offs2, int M, int E)
{
  __shared__ int wsum[4];
  const int tid = threadIdx.x, lane = tid & 63, w = tid >> 6;
  int idx = blockIdx.x * 1024 + tid * 4;
  int4 v = {0, 0, 0, 0};
  if (idx < M) v = *(const int4*)(deg2 + idx);
  int s4 = v.x + v.y + v.z + v.w;
  int s = s4;
  #pragma unroll
  for (int o = 1; o < 64; o <<= 1) { int t = __shfl_up(s, o); if (lane >= o) s += t; }
  if (lane == 63) wsum[w] = s;
  __syncthreads();
  if (tid == 0) {
    int a = wsum[0];
    a += wsum[1]; wsum[1] = a;
    a += wsum[2]; wsum[2] = a;
    a += wsum[3]; wsum[3] = a;
  }
  __syncthreads();
  int wbase = (w == 0) ? 0 : wsum[w - 1];
  int ebase = poff[blockIdx.x] + wbase + (s - s4);
  if (idx < M) {
    int4 o4;
    o4.x = ebase;
    o4.y = ebase + v.x;
    o4.z = ebase + v.x + v.y;
    o4.w = ebase + v.x + v.y + v.z;
    *(int4*)(offs2 + idx) = o4;
  }
  if (blockIdx.x == 0 && tid == 0) offs2[M] = E;  // all edges binned
}

// ---------------------------------------------------------------------------
// Kernel B: fuse-GEMM only (scan removed). LDS-staged, reads des directly:
// coalesced 512B row segments -> fp32->bf16 pack -> LDS [64][136] -> b128
// fragment reads -> MFMA.
// ---------------------------------------------------------------------------
__global__ __launch_bounds__(256) void k_fuse(
    const float* __restrict__ des, const float* __restrict__ nump, const float* __restrict__ catp,
    const u16* __restrict__ Wpk, const float* __restrict__ desB,
    const float* __restrict__ numW, const float* __restrict__ numB,
    const float* __restrict__ catW, const float* __restrict__ catB,
    const float* __restrict__ dg, const float* __restrict__ dbe, const float* __restrict__ dm, const float* __restrict__ dv,
    const float* __restrict__ ng, const float* __restrict__ nbe, const float* __restrict__ nm, const float* __restrict__ nv,
    const float* __restrict__ cg, const float* __restrict__ cbe, const float* __restrict__ cm, const float* __restrict__ cv,
    u16* __restrict__ x16, int n)
{
  const int tid  = threadIdx.x;
  const int lane = tid & 63;
  const int w    = tid >> 6;

  __shared__ float ync[64][66];                 // 16896 B
  __shared__ __align__(16) u16 atile[64 * 136]; // 17408 B, row stride 136 bf16

  const int quad = lane >> 4;
  const int l15  = lane & 15;
  const int fb   = blockIdx.x;
  const int rowbase = fb * 64 + 16 * w;

  {
    float nw[5], cw[6];
    #pragma unroll
    for (int j = 0; j < 5; ++j) nw[j] = numW[lane * 5 + j];
    #pragma unroll
    for (int j = 0; j < 6; ++j) cw[j] = catW[lane * 6 + j];
    float An = ng[lane] * rsqrtf(nv[lane] + BN_EPS);
    float Bn = (numB[lane] - nm[lane]) * An + nbe[lane];
    float Ac = cg[lane] * rsqrtf(cv[lane] + BN_EPS);
    float Bc = (catB[lane] - cm[lane]) * Ac + cbe[lane];
    for (int m = 0; m < 16; ++m) {
      int node = rowbase + m; if (node > n - 1) node = n - 1;
      float yn = 0.f, yc = 0.f;
      #pragma unroll
      for (int j = 0; j < 5; ++j) yn = fmaf(nump[node * 5 + j], nw[j], yn);
      #pragma unroll
      for (int j = 0; j < 6; ++j) yc = fmaf(catp[node * 6 + j], cw[j], yc);
      ync[16 * w + m][lane] = leaky(yn * An + Bn) + leaky(yc * Ac + Bc);
    }
  }

  float Ad4[4], Bd4[4];
  #pragma unroll
  for (int t = 0; t < 4; ++t) {
    int nn = 16 * t + l15;
    float A = dg[nn] * rsqrtf(dv[nn] + BN_EPS);
    Ad4[t] = A;
    Bd4[t] = (desB[nn] - dm[nn]) * A + dbe[nn];
  }
  __syncthreads();

  const u16* bP = Wpk + lane * 8;     // + kg*2048 + t*512, contiguous 1KB/wave

  f32x4 acc[4];
  #pragma unroll
  for (int t = 0; t < 4; ++t) acc[t] = (f32x4){0.f, 0.f, 0.f, 0.f};

  const int blk64 = fb * 64;
  for (int tile = 0; tile < 6; ++tile) {
    if (tile > 0) __syncthreads();   // all waves done reading previous tile
    #pragma unroll
    for (int it = 0; it < 4; ++it) {
      int j  = it * 256 + tid;        // 0..1023
      int r  = j >> 4;                // row-in-block 0..63
      int sg = j & 15;                // 8-float segment 0..15
      int row = blk64 + r; if (row > n - 1) row = n - 1;
      const float* p = des + (size_t)row * 768 + tile * 128 + sg * 8;
      float4 u = *(const float4*)p;
      float4 v = *(const float4*)(p + 4);
      u32* d = (u32*)(atile + r * 136 + sg * 8);
      d[0] = (u32)f2b(u.x) | ((u32)f2b(u.y) << 16);
      d[1] = (u32)f2b(u.z) | ((u32)f2b(u.w) << 16);
      d[2] = (u32)f2b(v.x) | ((u32)f2b(v.y) << 16);
      d[3] = (u32)f2b(v.z) | ((u32)f2b(v.w) << 16);
    }
    __syncthreads();
    #pragma unroll
    for (int kk = 0; kk < 4; ++kk) {
      bf16x8 a = *(const bf16x8*)(atile + (16 * w + l15) * 136 + kk * 32 + quad * 8);
      int kg = tile * 4 + kk;         // global K-step 0..23
      acc[0] = __builtin_amdgcn_mfma_f32_16x16x32_bf16(a, *(const bf16x8*)(bP + kg * 2048       ), acc[0], 0, 0, 0);
      acc[1] = __builtin_amdgcn_mfma_f32_16x16x32_bf16(a, *(const bf16x8*)(bP + kg * 2048 +  512), acc[1], 0, 0, 0);
      acc[2] = __builtin_amdgcn_mfma_f32_16x16x32_bf16(a, *(const bf16x8*)(bP + kg * 2048 + 1024), acc[2], 0, 0, 0);
      acc[3] = __builtin_amdgcn_mfma_f32_16x16x32_bf16(a, *(const bf16x8*)(bP + kg * 2048 + 1536), acc[3], 0, 0, 0);
    }
  }

  #pragma unroll
  for (int t = 0; t < 4; ++t) {
    #pragma unroll
    for (int r = 0; r < 4; ++r) {
      int m = quad * 4 + r;
      int node = rowbase + m;
      if (node < n) {
        int nn = 16 * t + l15;
        float v = leaky(acc[t][r] * Ad4[t] + Bd4[t]) + ync[16 * w + m][nn];
        x16[(size_t)node * 64 + nn] = f2b(v);
      }
    }
  }
}

// ---------------------------------------------------------------------------
// Kernel C: CSR placement sorted by (dst, rel). packed[pos] = src.
// ---------------------------------------------------------------------------
__global__ void k_place(const int* __restrict__ ei, const int* __restrict__ et, int E,
                        const int* __restrict__ offs2, int* __restrict__ cur2, int* __restrict__ packed)
{
  int e = blockIdx.x * 256 + threadIdx.x;
  if (e < E) {
    int bin = ei[E + e] * 2 + et[e];
    int pos = offs2[bin] + atomicAdd(&cur2[bin], 1);
    packed[pos] = ei[e];
  }
}

// ---------------------------------------------------------------------------
// Kernel D: pure gather/mean. Wave per node; lane = channel-pair (c=lane&31),
// half-wave = edge substream -> one u32 wave-load gathers TWO edges' rows.
// ---------------------------------------------------------------------------
__global__ __launch_bounds__(256) void k_agg(
    const u16* __restrict__ x16, const int* __restrict__ offs2, const int* __restrict__ packed,
    u32* __restrict__ agg, int n)
{
  const int tid = threadIdx.x, lane = tid & 63, w = tid >> 6;
  const int c = lane & 31, half = lane >> 5;

  for (int nd = blockIdx.x * 4 + w; nd < n; nd += gridDim.x * 4) {
    int o0 = offs2[nd * 2], o1 = offs2[nd * 2 + 1], o2 = offs2[nd * 2 + 2];
    float aE[2], aO[2];

    #pragma unroll
    for (int rel = 0; rel < 2; ++rel) {
      int beg = rel ? o1 : o0;
      int end = rel ? o2 : o1;
      float accE = 0.f, accO = 0.f;
      for (int j0 = beg; j0 < end; j0 += 64) {
        int idx = j0 + lane;
        int p = (idx < end) ? packed[idx] : 0;
        p = (p < 0) ? 0 : ((p > n - 1) ? (n - 1) : p);
        int cn = end - j0; if (cn > 64) cn = 64;
        int t = 0;
        for (; t + 16 <= cn; t += 16) {        // 16 edges: 8 dual-edge loads in flight
          int s0 = __shfl(p, t      + half);
          int s1 = __shfl(p, t + 2  + half);
          int s2 = __shfl(p, t + 4  + half);
          int s3 = __shfl(p, t + 6  + half);
          int s4 = __shfl(p, t + 8  + half);
          int s5 = __shfl(p, t + 10 + half);
          int s6 = __shfl(p, t + 12 + half);
          int s7 = __shfl(p, t + 14 + half);
          u32 v0 = *(const u32*)(x16 + (size_t)s0 * 64 + 2 * c);
          u32 v1 = *(const u32*)(x16 + (size_t)s1 * 64 + 2 * c);
          u32 v2 = *(const u32*)(x16 + (size_t)s2 * 64 + 2 * c);
          u32 v3 = *(const u32*)(x16 + (size_t)s3 * 64 + 2 * c);
          u32 v4 = *(const u32*)(x16 + (size_t)s4 * 64 + 2 * c);
          u32 v5 = *(const u32*)(x16 + (size_t)s5 * 64 + 2 * c);
          u32 v6 = *(const u32*)(x16 + (size_t)s6 * 64 + 2 * c);
          u32 v7 = *(const u32*)(x16 + (size_t)s7 * 64 + 2 * c);
          accE += ((bl(v0) + bl(v1)) + (bl(v2) + bl(v3))) + ((bl(v4) + bl(v5)) + (bl(v6) + bl(v7)));
          accO += ((bh(v0) + bh(v1)) + (bh(v2) + bh(v3))) + ((bh(v4) + bh(v5)) + (bh(v6) + bh(v7)));
        }
        for (; t + 8 <= cn; t += 8) {          // 8 edges: 4 dual-edge loads
          int s0 = __shfl(p, t     + half);
          int s1 = __shfl(p, t + 2 + half);
          int s2 = __shfl(p, t + 4 + half);
          int s3 = __shfl(p, t + 6 + half);
          u32 v0 = *(const u32*)(x16 + (size_t)s0 * 64 + 2 * c);
          u32 v1 = *(const u32*)(x16 + (size_t)s1 * 64 + 2 * c);
          u32 v2 = *(const u32*)(x16 + (size_t)s2 * 64 + 2 * c);
          u32 v3 = *(const u32*)(x16 + (size_t)s3 * 64 + 2 * c);
          accE += (bl(v0) + bl(v1)) + (bl(v2) + bl(v3));
          accO += (bh(v0) + bh(v1)) + (bh(v2) + bh(v3));
        }
        for (; t + 2 <= cn; t += 2) {          // 2 edges per load
          int s0 = __shfl(p, t + half);
          u32 v0 = *(const u32*)(x16 + (size_t)s0 * 64 + 2 * c);
          accE += bl(v0); accO += bh(v0);
        }
        if (t < cn) {                           // odd remainder: half 0 only
          int s0 = __shfl(p, t);
          if (half == 0) {
            u32 v0 = *(const u32*)(x16 + (size_t)s0 * 64 + 2 * c);
            accE += bl(v0); accO += bh(v0);
          }
        }
      }
      accE += __shfl_xor(accE, 32);
      accO += __shfl_xor(accO, 32);
      int cnt = end - beg;
      float sc = 1.f / (float)(cnt > 1 ? cnt : 1);
      aE[rel] = accE * sc;
      aO[rel] = accO * sc;
    }

    float sE = half ? aE[1] : aE[0];
    float sO = half ? aO[1] : aO[0];
    agg[(size_t)nd * 64 + lane] = (u32)f2b(sE) | ((u32)f2b(sO) << 16);
  }
}

// ---------------------------------------------------------------------------
// Kernel E: batched MFMA MLP.  A = agg[node][128] bf16.
// ---------------------------------------------------------------------------
__global__ __launch_bounds__(256) void k_mlp(
    const u32* __restrict__ agg, const u16* __restrict__ Wmlp, const u16* __restrict__ W1p,
    const float* __restrict__ b1, const float* __restrict__ W2, const float* __restrict__ b2,
    float2* __restrict__ out, int n)
{
  __shared__ __align__(16) u16 h1[4][16][72];   // [wave][node m][ch 0..63]
  __shared__ float h2[4][16][34];               // [wave][node m][j 0..31]

  const int tid = threadIdx.x, lane = tid & 63, w = tid >> 6;
  const int quad = lane >> 4, l15 = lane & 15;
  const int rowbase = blockIdx.x * 64 + 16 * w;

  int rowA = rowbase + l15; if (rowA > n - 1) rowA = n - 1;
  const u16* aRow = (const u16*)(agg + (size_t)rowA * 64);   // 128 bf16

  // ---- GEMM1: [16 nodes x 128] @ [128 -> 64] ----
  f32x4 acc[4];
  #pragma unroll
  for (int t = 0; t < 4; ++t) acc[t] = (f32x4){0.f, 0.f, 0.f, 0.f};
  #pragma unroll
  for (int ks = 0; ks < 4; ++ks) {
    bf16x8 a = *(const bf16x8*)(aRow + ks * 32 + quad * 8);
    #pragma unroll
    for (int t = 0; t < 4; ++t) {
      bf16x8 b = *(const bf16x8*)(Wmlp + (size_t)(16 * t + l15) * 128 + ks * 32 + quad * 8);
      acc[t] = __builtin_amdgcn_mfma_f32_16x16x32_bf16(a, b, acc[t], 0, 0, 0);
    }
  }
  #pragma unroll
  for (int t = 0; t < 4; ++t)
    #pragma unroll
    for (int r = 0; r < 4; ++r) {
      int m = quad * 4 + r;
      h1[w][m][16 * t + l15] = f2b(leaky(0.5f * acc[t][r]));
    }
  __syncthreads();

  // ---- GEMM2: [16 x 64] @ [64 -> 32] ----
  f32x4 acc2[2];
  acc2[0] = (f32x4){0.f, 0.f, 0.f, 0.f};
  acc2[1] = (f32x4){0.f, 0.f, 0.f, 0.f};
  #pragma unroll
  for (int ks = 0; ks < 2; ++ks) {
    bf16x8 a = *(const bf16x8*)(&h1[w][l15][ks * 32 + quad * 8]);
    #pragma unroll
    for (int t = 0; t < 2; ++t) {
      bf16x8 b = *(const bf16x8*)(W1p + (size_t)(16 * t + l15) * 64 + ks * 32 + quad * 8);
      acc2[t] = __builtin_amdgcn_mfma_f32_16x16x32_bf16(a, b, acc2[t], 0, 0, 0);
    }
  }
  #pragma unroll
  for (int t = 0; t < 2; ++t)
    #pragma unroll
    for (int r = 0; r < 4; ++r) {
      int m = quad * 4 + r;
      int j = 16 * t + l15;
      h2[w][m][j] = leaky(acc2[t][r] + b1[j]);
    }
  __syncthreads();

  // ---- final 32 -> 2 ----
  float t0 = 0.f, t1 = 0.f;
  #pragma unroll
  for (int jj = 0; jj < 8; ++jj) {
    int j = quad * 8 + jj;
    float hv = h2[w][l15][j];
    t0 = fmaf(hv, W2[j], t0);
    t1 = fmaf(hv, W2[32 + j], t1);
  }
  t0 += __shfl_xor(t0, 16); t0 += __shfl_xor(t0, 32);
  t1 += __shfl_xor(t1, 16); t1 += __shfl_xor(t1, 32);
  int node = rowbase + l15;
  if (quad == 0 && node < n) {
    float2 q; q.x = t0 + b2[0]; q.y = t1 + b2[1];
    out[node] = q;
  }
}

// ---------------------------------------------------------------------------
extern "C" void kernel_launch(void* const* d_in, const int* in_sizes, int n_in,
                              void* d_out, int out_size, void* d_ws, size_t ws_size,
                              hipStream_t stream)
{
  const float* des  = (const float*)d_in[0];
  const float* nump = (const float*)d_in[1];
  const float* catp = (const float*)d_in[2];
  const int* ei   = (const int*)d_in[3];
  const int* et   = (const int*)d_in[4];
  const float* desW = (const float*)d_in[5];
  const float* desB = (const float*)d_in[6];
  const float* numW = (const float*)d_in[7];
  const float* numB = (const float*)d_in[8];
  const float* catW = (const float*)d_in[9];
  const float* catB = (const float*)d_in[10];
  const float* dg  = (const float*)d_in[11];
  const float* dbe = (const float*)d_in[12];
  const float* dm  = (const float*)d_in[13];
  const float* dv  = (const float*)d_in[14];
  const float* ng  = (const float*)d_in[15];
  const float* nbe = (const float*)d_in[16];
  const float* nm  = (const float*)d_in[17];
  const float* nv  = (const float*)d_in[18];
  const float* cg  = (const float*)d_in[19];
  const float* cbe = (const float*)d_in[20];
  const float* cm  = (const float*)d_in[21];
  const float* cv  = (const float*)d_in[22];
  const float* rgcnW = (const float*)d_in[23];
  const float* W1 = (const float*)d_in[24];
  const float* b1 = (const float*)d_in[25];
  const float* W2 = (const float*)d_in[26];
  const float* b2 = (const float*)d_in[27];

  const int N = in_sizes[1] / 5;   // num is (N,5)
  const int E = in_sizes[4];       // edge_type is (E,)
  const int M = 2 * N;             // (dst, rel) bins
  const int NB = (N + 63) / 64;    // node blocks (64 rows each)
  const int NCH = (M + 1023) / 1024;  // scan chunks (196)

  // workspace layout
  char* ws = (char*)d_ws;
  u16* tab    = (u16*)ws;                  size_t off = (size_t)59392 * 2;      // weight tables
  off = (off + 255) & ~(size_t)255;
  u16* x16    = (u16*)(ws + off);          off += (size_t)N * 64 * 2;
  u32* agg    = (u32*)(ws + off);          off += (size_t)N * 64 * 4;
  int* deg2   = (int*)(ws + off);          off += (size_t)M * 4;
  int* cur2   = (int*)(ws + off);          off += (size_t)M * 4;
  int* offs2  = (int*)(ws + off);          off += (size_t)(M + 1) * 4;
  off = (off + 255) & ~(size_t)255;
  int* psum   = (int*)(ws + off);          off += (size_t)NCH * 4;
  int* poff   = (int*)(ws + off);          off += (size_t)NCH * 4;
  off = (off + 255) & ~(size_t)255;
  int* packed = (int*)(ws + off);

  u16* Wpk    = tab;
  u16* Wmlp   = tab + 49152;
  u16* W1p    = tab + 57344;

  hipMemsetAsync(deg2, 0, (size_t)M * 8, stream);     // zero deg2 + cur2 (adjacent)

  const int HB = (E + 255) / 256;
  const int PB = (59392 + 255) / 256;
  k_hist_prep<<<HB + PB, 256, 0, stream>>>(ei, et, E, HB, deg2, desW, rgcnW, W1, tab);

  k_fuse<<<NB, 256, 0, stream>>>(des, nump, catp, Wpk, desB, numW, numB, catW, catB,
                                 dg, dbe, dm, dv, ng, nbe, nm, nv, cg, cbe, cm, cv,
                                 x16, N);

  k_scanA<<<NCH, 256, 0, stream>>>(deg2, psum, M);
  k_scanB<<<1, 256, 0, stream>>>(psum, poff, NCH);
  k_scanC<<<NCH, 256, 0, stream>>>(deg2, poff, offs2, M, E);

  k_place<<<(E + 255) / 256, 256, 0, stream>>>(ei, et, E, offs2, cur2, packed);
  k_agg<<<2048, 256, 0, stream>>>(x16, offs2, packed, agg, N);
  k_mlp<<<(N + 63) / 64, 256, 0, stream>>>(agg, Wmlp, W1p, b1, W2, b2, (float2*)d_out, N);
}

// Round 11
// 852.595 us; speedup vs baseline: 1.5726x; 1.0233x over previous
//
#include <hip/hip_runtime.h>

typedef unsigned int u32;
typedef unsigned short u16;

#define NEG 0.01f
#define BN_EPS 1e-5f

typedef __attribute__((ext_vector_type(8))) short bf16x8;
typedef __attribute__((ext_vector_type(4))) float f32x4;

__device__ __forceinline__ float bl(u32 u){ union { u32 i; float f; } c; c.i = u << 16; return c.f; }
__device__ __forceinline__ float bh(u32 u){ union { u32 i; float f; } c; c.i = u & 0xFFFF0000u; return c.f; }
__device__ __forceinline__ u16 f2b(float f){
  union { float f; u32 i; } c; c.f = f;
  u32 t = c.i + 0x7FFFu + ((c.i >> 16) & 1u);
  return (u16)(t >> 16);
}
__device__ __forceinline__ float leaky(float v){ return v > 0.f ? v : NEG * v; }

// ---------------------------------------------------------------------------
// Kernel 1: fused [fuse-GEMM | hist | prep] — all mutually independent now:
// fuse self-stages W from desWf (fp32, L2-resident) into LDS per K-tile, so
// the old prep->fuse dependency on Wpk is gone. Fuse blocks first (the pole,
// HBM-bound); hist blocks (latency-bound atomics) + prep backfill behind.
//  blocks [0, FB)            : fusion GEMM -> x16[node][64] bf16
//  blocks [FB, FB+HB)        : per-(dst,rel) histogram, bin = dst*2 + rel
//  blocks [FB+HB, FB+HB+40)  : prep Wmlp/W1p bf16 tables (tab[49152..59392))
// ---------------------------------------------------------------------------
__global__ __launch_bounds__(256) void k_fuse_hist_prep(
    const float* __restrict__ des, const float* __restrict__ nump, const float* __restrict__ catp,
    const float* __restrict__ desWf, const float* __restrict__ desB,
    const float* __restrict__ numW, const float* __restrict__ numB,
    const float* __restrict__ catW, const float* __restrict__ catB,
    const float* __restrict__ dg, const float* __restrict__ dbe, const float* __restrict__ dm, const float* __restrict__ dv,
    const float* __restrict__ ng, const float* __restrict__ nbe, const float* __restrict__ nm, const float* __restrict__ nv,
    const float* __restrict__ cg, const float* __restrict__ cbe, const float* __restrict__ cm, const float* __restrict__ cv,
    u16* __restrict__ x16, int n, int FB,
    const int* __restrict__ ei, const int* __restrict__ et, int E, int HB,
    int* __restrict__ deg2,
    const float* __restrict__ rgcnW, const float* __restrict__ W1, u16* __restrict__ tab)
{
  const int tid  = threadIdx.x;
  const int bid  = blockIdx.x;

  if (bid >= FB) {
    int rb = bid - FB;
    if (rb < HB) {
      int e = rb * 256 + tid;
      if (e < E) atomicAdd(&deg2[ei[E + e] * 2 + et[e]], 1);
    } else {
      int i = 49152 + (rb - HB) * 256 + tid;
      if (i < 57344) {
        int j = i - 49152;            // h*128 + k
        int h = j >> 7, k = j & 127;
        tab[i] = f2b(rgcnW[(k >= 64 ? 4096 : 0) + h * 64 + (k & 63)]);
      } else if (i < 59392) {
        tab[i] = f2b(W1[i - 57344]);
      }
    }
    return;
  }

  // ---- fusion GEMM ----
  const int lane = tid & 63;
  const int w    = tid >> 6;
  __shared__ float ync[64][66];                  // 16896 B
  __shared__ __align__(16) u16 atile[64 * 136];  // 17408 B (A: des tile)
  __shared__ __align__(16) u16 btile[64 * 136];  // 17408 B (B: W tile)

  const int quad = lane >> 4;
  const int l15  = lane & 15;
  const int fb   = bid;
  const int rowbase = fb * 64 + 16 * w;

  {
    float nw[5], cw[6];
    #pragma unroll
    for (int j = 0; j < 5; ++j) nw[j] = numW[lane * 5 + j];
    #pragma unroll
    for (int j = 0; j < 6; ++j) cw[j] = catW[lane * 6 + j];
    float An = ng[lane] * rsqrtf(nv[lane] + BN_EPS);
    float Bn = (numB[lane] - nm[lane]) * An + nbe[lane];
    float Ac = cg[lane] * rsqrtf(cv[lane] + BN_EPS);
    float Bc = (catB[lane] - cm[lane]) * Ac + cbe[lane];
    for (int m = 0; m < 16; ++m) {
      int node = rowbase + m; if (node > n - 1) node = n - 1;
      float yn = 0.f, yc = 0.f;
      #pragma unroll
      for (int j = 0; j < 5; ++j) yn = fmaf(nump[node * 5 + j], nw[j], yn);
      #pragma unroll
      for (int j = 0; j < 6; ++j) yc = fmaf(catp[node * 6 + j], cw[j], yc);
      ync[16 * w + m][lane] = leaky(yn * An + Bn) + leaky(yc * Ac + Bc);
    }
  }

  float Ad4[4], Bd4[4];
  #pragma unroll
  for (int t = 0; t < 4; ++t) {
    int nn = 16 * t + l15;
    float A = dg[nn] * rsqrtf(dv[nn] + BN_EPS);
    Ad4[t] = A;
    Bd4[t] = (desB[nn] - dm[nn]) * A + dbe[nn];
  }
  __syncthreads();

  f32x4 acc[4];
  #pragma unroll
  for (int t = 0; t < 4; ++t) acc[t] = (f32x4){0.f, 0.f, 0.f, 0.f};

  const int blk64 = fb * 64;
  for (int tile = 0; tile < 6; ++tile) {
    if (tile > 0) __syncthreads();   // all waves done reading previous tiles
    // ---- stage A: 64 rows x 128 cols of des (fp32 -> bf16), coalesced ----
    #pragma unroll
    for (int it = 0; it < 4; ++it) {
      int j  = it * 256 + tid;        // 0..1023
      int r  = j >> 4;                // row-in-block 0..63
      int sg = j & 15;                // 8-float segment 0..15
      int row = blk64 + r; if (row > n - 1) row = n - 1;
      const float* p = des + (size_t)row * 768 + tile * 128 + sg * 8;
      float4 u = *(const float4*)p;
      float4 v = *(const float4*)(p + 4);
      u32* d = (u32*)(atile + r * 136 + sg * 8);
      d[0] = (u32)f2b(u.x) | ((u32)f2b(u.y) << 16);
      d[1] = (u32)f2b(u.z) | ((u32)f2b(u.w) << 16);
      d[2] = (u32)f2b(v.x) | ((u32)f2b(v.y) << 16);
      d[3] = (u32)f2b(v.z) | ((u32)f2b(v.w) << 16);
    }
    // ---- stage B: 64 rows x 128 cols of W (fp32 -> bf16, L2-resident) ----
    #pragma unroll
    for (int it = 0; it < 4; ++it) {
      int j  = it * 256 + tid;
      int r  = j >> 4;                // W row 0..63 (always valid, H=64)
      int sg = j & 15;
      const float* p = desWf + (size_t)r * 768 + tile * 128 + sg * 8;
      float4 u = *(const float4*)p;
      float4 v = *(const float4*)(p + 4);
      u32* d = (u32*)(btile + r * 136 + sg * 8);
      d[0] = (u32)f2b(u.x) | ((u32)f2b(u.y) << 16);
      d[1] = (u32)f2b(u.z) | ((u32)f2b(u.w) << 16);
      d[2] = (u32)f2b(v.x) | ((u32)f2b(v.y) << 16);
      d[3] = (u32)f2b(v.z) | ((u32)f2b(v.w) << 16);
    }
    __syncthreads();
    // ---- 4 K-steps of MFMA from LDS fragments ----
    #pragma unroll
    for (int kk = 0; kk < 4; ++kk) {
      bf16x8 a = *(const bf16x8*)(atile + (16 * w + l15) * 136 + kk * 32 + quad * 8);
      acc[0] = __builtin_amdgcn_mfma_f32_16x16x32_bf16(a, *(const bf16x8*)(btile + (     l15) * 136 + kk * 32 + quad * 8), acc[0], 0, 0, 0);
      acc[1] = __builtin_amdgcn_mfma_f32_16x16x32_bf16(a, *(const bf16x8*)(btile + (16 + l15) * 136 + kk * 32 + quad * 8), acc[1], 0, 0, 0);
      acc[2] = __builtin_amdgcn_mfma_f32_16x16x32_bf16(a, *(const bf16x8*)(btile + (32 + l15) * 136 + kk * 32 + quad * 8), acc[2], 0, 0, 0);
      acc[3] = __builtin_amdgcn_mfma_f32_16x16x32_bf16(a, *(const bf16x8*)(btile + (48 + l15) * 136 + kk * 32 + quad * 8), acc[3], 0, 0, 0);
    }
  }

  #pragma unroll
  for (int t = 0; t < 4; ++t) {
    #pragma unroll
    for (int r = 0; r < 4; ++r) {
      int m = quad * 4 + r;
      int node = rowbase + m;
      if (node < n) {
        int nn = 16 * t + l15;
        float v = leaky(acc[t][r] * Ad4[t] + Bd4[t]) + ync[16 * w + m][nn];
        x16[(size_t)node * 64 + nn] = f2b(v);
      }
    }
  }
}

// ---------------------------------------------------------------------------
// Parallel scan over M bins (3 stages; replaced the 219us serial scan pole).
// ---------------------------------------------------------------------------
__global__ __launch_bounds__(256) void k_scanA(
    const int* __restrict__ deg2, int* __restrict__ psum, int M)
{
  __shared__ int ws4[4];
  const int tid = threadIdx.x, lane = tid & 63, w = tid >> 6;
  int idx = blockIdx.x * 1024 + tid * 4;
  int4 v = {0, 0, 0, 0};
  if (idx < M) v = *(const int4*)(deg2 + idx);
  int s = v.x + v.y + v.z + v.w;
  #pragma unroll
  for (int o = 1; o < 64; o <<= 1) s += __shfl_xor(s, o);
  if (lane == 0) ws4[w] = s;
  __syncthreads();
  if (tid == 0) psum[blockIdx.x] = ws4[0] + ws4[1] + ws4[2] + ws4[3];
}

__global__ __launch_bounds__(256) void k_scanB(
    const int* __restrict__ psum, int* __restrict__ poff, int NCH)
{
  __shared__ int wsum[4];
  const int tid = threadIdx.x, lane = tid & 63, w = tid >> 6;
  int v = (tid < NCH) ? psum[tid] : 0;
  int s = v;
  #pragma unroll
  for (int o = 1; o < 64; o <<= 1) { int t = __shfl_up(s, o); if (lane >= o) s += t; }
  if (lane == 63) wsum[w] = s;
  __syncthreads();
  if (tid == 0) {
    int a = wsum[0];
    a += wsum[1]; wsum[1] = a;
    a += wsum[2]; wsum[2] = a;
    a += wsum[3]; wsum[3] = a;
  }
  __syncthreads();
  int wbase = (w == 0) ? 0 : wsum[w - 1];
  if (tid < NCH) poff[tid] = wbase + (s - v);
}

__global__ __launch_bounds__(256) void k_scanC(
    const int* __restrict__ deg2, const int* __restrict__ poff,
    int* __restrict__ offs2, int M, int E)
{
  __shared__ int wsum[4];
  const int tid = threadIdx.x, lane = tid & 63, w = tid >> 6;
  int idx = blockIdx.x * 1024 + tid * 4;
  int4 v = {0, 0, 0, 0};
  if (idx < M) v = *(const int4*)(deg2 + idx);
  int s4 = v.x + v.y + v.z + v.w;
  int s = s4;
  #pragma unroll
  for (int o = 1; o < 64; o <<= 1) { int t = __shfl_up(s, o); if (lane >= o) s += t; }
  if (lane == 63) wsum[w] = s;
  __syncthreads();
  if (tid == 0) {
    int a = wsum[0];
    a += wsum[1]; wsum[1] = a;
    a += wsum[2]; wsum[2] = a;
    a += wsum[3]; wsum[3] = a;
  }
  __syncthreads();
  int wbase = (w == 0) ? 0 : wsum[w - 1];
  int ebase = poff[blockIdx.x] + wbase + (s - s4);
  if (idx < M) {
    int4 o4;
    o4.x = ebase;
    o4.y = ebase + v.x;
    o4.z = ebase + v.x + v.y;
    o4.w = ebase + v.x + v.y + v.z;
    *(int4*)(offs2 + idx) = o4;
  }
  if (blockIdx.x == 0 && tid == 0) offs2[M] = E;  // all edges binned
}

// ---------------------------------------------------------------------------
// Kernel C: CSR placement sorted by (dst, rel). packed[pos] = src.
// ---------------------------------------------------------------------------
__global__ void k_place(const int* __restrict__ ei, const int* __restrict__ et, int E,
                        const int* __restrict__ offs2, int* __restrict__ cur2, int* __restrict__ packed)
{
  int e = blockIdx.x * 256 + threadIdx.x;
  if (e < E) {
    int bin = ei[E + e] * 2 + et[e];
    int pos = offs2[bin] + atomicAdd(&cur2[bin], 1);
    packed[pos] = ei[e];
  }
}

// ---------------------------------------------------------------------------
// Kernel D: pure gather/mean. Wave per node; lane = channel-pair (c=lane&31),
// half-wave = edge substream -> one u32 wave-load gathers TWO edges' rows.
// ---------------------------------------------------------------------------
__global__ __launch_bounds__(256) void k_agg(
    const u16* __restrict__ x16, const int* __restrict__ offs2, const int* __restrict__ packed,
    u32* __restrict__ agg, int n)
{
  const int tid = threadIdx.x, lane = tid & 63, w = tid >> 6;
  const int c = lane & 31, half = lane >> 5;

  for (int nd = blockIdx.x * 4 + w; nd < n; nd += gridDim.x * 4) {
    int o0 = offs2[nd * 2], o1 = offs2[nd * 2 + 1], o2 = offs2[nd * 2 + 2];
    float aE[2], aO[2];

    #pragma unroll
    for (int rel = 0; rel < 2; ++rel) {
      int beg = rel ? o1 : o0;
      int end = rel ? o2 : o1;
      float accE = 0.f, accO = 0.f;
      for (int j0 = beg; j0 < end; j0 += 64) {
        int idx = j0 + lane;
        int p = (idx < end) ? packed[idx] : 0;
        p = (p < 0) ? 0 : ((p > n - 1) ? (n - 1) : p);
        int cn = end - j0; if (cn > 64) cn = 64;
        int t = 0;
        for (; t + 16 <= cn; t += 16) {        // 16 edges: 8 dual-edge loads in flight
          int s0 = __shfl(p, t      + half);
          int s1 = __shfl(p, t + 2  + half);
          int s2 = __shfl(p, t + 4  + half);
          int s3 = __shfl(p, t + 6  + half);
          int s4 = __shfl(p, t + 8  + half);
          int s5 = __shfl(p, t + 10 + half);
          int s6 = __shfl(p, t + 12 + half);
          int s7 = __shfl(p, t + 14 + half);
          u32 v0 = *(const u32*)(x16 + (size_t)s0 * 64 + 2 * c);
          u32 v1 = *(const u32*)(x16 + (size_t)s1 * 64 + 2 * c);
          u32 v2 = *(const u32*)(x16 + (size_t)s2 * 64 + 2 * c);
          u32 v3 = *(const u32*)(x16 + (size_t)s3 * 64 + 2 * c);
          u32 v4 = *(const u32*)(x16 + (size_t)s4 * 64 + 2 * c);
          u32 v5 = *(const u32*)(x16 + (size_t)s5 * 64 + 2 * c);
          u32 v6 = *(const u32*)(x16 + (size_t)s6 * 64 + 2 * c);
          u32 v7 = *(const u32*)(x16 + (size_t)s7 * 64 + 2 * c);
          accE += ((bl(v0) + bl(v1)) + (bl(v2) + bl(v3))) + ((bl(v4) + bl(v5)) + (bl(v6) + bl(v7)));
          accO += ((bh(v0) + bh(v1)) + (bh(v2) + bh(v3))) + ((bh(v4) + bh(v5)) + (bh(v6) + bh(v7)));
        }
        for (; t + 8 <= cn; t += 8) {          // 8 edges: 4 dual-edge loads
          int s0 = __shfl(p, t     + half);
          int s1 = __shfl(p, t + 2 + half);
          int s2 = __shfl(p, t + 4 + half);
          int s3 = __shfl(p, t + 6 + half);
          u32 v0 = *(const u32*)(x16 + (size_t)s0 * 64 + 2 * c);
          u32 v1 = *(const u32*)(x16 + (size_t)s1 * 64 + 2 * c);
          u32 v2 = *(const u32*)(x16 + (size_t)s2 * 64 + 2 * c);
          u32 v3 = *(const u32*)(x16 + (size_t)s3 * 64 + 2 * c);
          accE += (bl(v0) + bl(v1)) + (bl(v2) + bl(v3));
          accO += (bh(v0) + bh(v1)) + (bh(v2) + bh(v3));
        }
        for (; t + 2 <= cn; t += 2) {          // 2 edges per load
          int s0 = __shfl(p, t + half);
          u32 v0 = *(const u32*)(x16 + (size_t)s0 * 64 + 2 * c);
          accE += bl(v0); accO += bh(v0);
        }
        if (t < cn) {                           // odd remainder: half 0 only
          int s0 = __shfl(p, t);
          if (half == 0) {
            u32 v0 = *(const u32*)(x16 + (size_t)s0 * 64 + 2 * c);
            accE += bl(v0); accO += bh(v0);
          }
        }
      }
      accE += __shfl_xor(accE, 32);
      accO += __shfl_xor(accO, 32);
      int cnt = end - beg;
      float sc = 1.f / (float)(cnt > 1 ? cnt : 1);
      aE[rel] = accE * sc;
      aO[rel] = accO * sc;
    }

    float sE = half ? aE[1] : aE[0];
    float sO = half ? aO[1] : aO[0];
    agg[(size_t)nd * 64 + lane] = (u32)f2b(sE) | ((u32)f2b(sO) << 16);
  }
}

// ---------------------------------------------------------------------------
// Kernel E: batched MFMA MLP.  A = agg[node][128] bf16.
// ---------------------------------------------------------------------------
__global__ __launch_bounds__(256) void k_mlp(
    const u32* __restrict__ agg, const u16* __restrict__ Wmlp, const u16* __restrict__ W1p,
    const float* __restrict__ b1, const float* __restrict__ W2, const float* __restrict__ b2,
    float2* __restrict__ out, int n)
{
  __shared__ __align__(16) u16 h1[4][16][72];   // [wave][node m][ch 0..63]
  __shared__ float h2[4][16][34];               // [wave][node m][j 0..31]

  const int tid = threadIdx.x, lane = tid & 63, w = tid >> 6;
  const int quad = lane >> 4, l15 = lane & 15;
  const int rowbase = blockIdx.x * 64 + 16 * w;

  int rowA = rowbase + l15; if (rowA > n - 1) rowA = n - 1;
  const u16* aRow = (const u16*)(agg + (size_t)rowA * 64);   // 128 bf16

  // ---- GEMM1: [16 nodes x 128] @ [128 -> 64] ----
  f32x4 acc[4];
  #pragma unroll
  for (int t = 0; t < 4; ++t) acc[t] = (f32x4){0.f, 0.f, 0.f, 0.f};
  #pragma unroll
  for (int ks = 0; ks < 4; ++ks) {
    bf16x8 a = *(const bf16x8*)(aRow + ks * 32 + quad * 8);
    #pragma unroll
    for (int t = 0; t < 4; ++t) {
      bf16x8 b = *(const bf16x8*)(Wmlp + (size_t)(16 * t + l15) * 128 + ks * 32 + quad * 8);
      acc[t] = __builtin_amdgcn_mfma_f32_16x16x32_bf16(a, b, acc[t], 0, 0, 0);
    }
  }
  #pragma unroll
  for (int t = 0; t < 4; ++t)
    #pragma unroll
    for (int r = 0; r < 4; ++r) {
      int m = quad * 4 + r;
      h1[w][m][16 * t + l15] = f2b(leaky(0.5f * acc[t][r]));
    }
  __syncthreads();

  // ---- GEMM2: [16 x 64] @ [64 -> 32] ----
  f32x4 acc2[2];
  acc2[0] = (f32x4){0.f, 0.f, 0.f, 0.f};
  acc2[1] = (f32x4){0.f, 0.f, 0.f, 0.f};
  #pragma unroll
  for (int ks = 0; ks < 2; ++ks) {
    bf16x8 a = *(const bf16x8*)(&h1[w][l15][ks * 32 + quad * 8]);
    #pragma unroll
    for (int t = 0; t < 2; ++t) {
      bf16x8 b = *(const bf16x8*)(W1p + (size_t)(16 * t + l15) * 64 + ks * 32 + quad * 8);
      acc2[t] = __builtin_amdgcn_mfma_f32_16x16x32_bf16(a, b, acc2[t], 0, 0, 0);
    }
  }
  #pragma unroll
  for (int t = 0; t < 2; ++t)
    #pragma unroll
    for (int r = 0; r < 4; ++r) {
      int m = quad * 4 + r;
      int j = 16 * t + l15;
      h2[w][m][j] = leaky(acc2[t][r] + b1[j]);
    }
  __syncthreads();

  // ---- final 32 -> 2 ----
  float t0 = 0.f, t1 = 0.f;
  #pragma unroll
  for (int jj = 0; jj < 8; ++jj) {
    int j = quad * 8 + jj;
    float hv = h2[w][l15][j];
    t0 = fmaf(hv, W2[j], t0);
    t1 = fmaf(hv, W2[32 + j], t1);
  }
  t0 += __shfl_xor(t0, 16); t0 += __shfl_xor(t0, 32);
  t1 += __shfl_xor(t1, 16); t1 += __shfl_xor(t1, 32);
  int node = rowbase + l15;
  if (quad == 0 && node < n) {
    float2 q; q.x = t0 + b2[0]; q.y = t1 + b2[1];
    out[node] = q;
  }
}

// ---------------------------------------------------------------------------
extern "C" void kernel_launch(void* const* d_in, const int* in_sizes, int n_in,
                              void* d_out, int out_size, void* d_ws, size_t ws_size,
                              hipStream_t stream)
{
  const float* des  = (const float*)d_in[0];
  const float* nump = (const float*)d_in[1];
  const float* catp = (const float*)d_in[2];
  const int* ei   = (const int*)d_in[3];
  const int* et   = (const int*)d_in[4];
  const float* desW = (const float*)d_in[5];
  const float* desB = (const float*)d_in[6];
  const float* numW = (const float*)d_in[7];
  const float* numB = (const float*)d_in[8];
  const float* catW = (const float*)d_in[9];
  const float* catB = (const float*)d_in[10];
  const float* dg  = (const float*)d_in[11];
  const float* dbe = (const float*)d_in[12];
  const float* dm  = (const float*)d_in[13];
  const float* dv  = (const float*)d_in[14];
  const float* ng  = (const float*)d_in[15];
  const float* nbe = (const float*)d_in[16];
  const float* nm  = (const float*)d_in[17];
  const float* nv  = (const float*)d_in[18];
  const float* cg  = (const float*)d_in[19];
  const float* cbe = (const float*)d_in[20];
  const float* cm  = (const float*)d_in[21];
  const float* cv  = (const float*)d_in[22];
  const float* rgcnW = (const float*)d_in[23];
  const float* W1 = (const float*)d_in[24];
  const float* b1 = (const float*)d_in[25];
  const float* W2 = (const float*)d_in[26];
  const float* b2 = (const float*)d_in[27];

  const int N = in_sizes[1] / 5;   // num is (N,5)
  const int E = in_sizes[4];       // edge_type is (E,)
  const int M = 2 * N;             // (dst, rel) bins
  const int NB = (N + 63) / 64;    // node blocks (64 rows each)
  const int NCH = (M + 1023) / 1024;  // scan chunks

  // workspace layout
  char* ws = (char*)d_ws;
  u16* tab    = (u16*)ws;                  size_t off = (size_t)59392 * 2;      // weight tables
  off = (off + 255) & ~(size_t)255;
  u16* x16    = (u16*)(ws + off);          off += (size_t)N * 64 * 2;
  u32* agg    = (u32*)(ws + off);          off += (size_t)N * 64 * 4;
  int* deg2   = (int*)(ws + off);          off += (size_t)M * 4;
  int* cur2   = (int*)(ws + off);          off += (size_t)M * 4;
  int* offs2  = (int*)(ws + off);          off += (size_t)(M + 1) * 4;
  off = (off + 255) & ~(size_t)255;
  int* psum   = (int*)(ws + off);          off += (size_t)NCH * 4;
  int* poff   = (int*)(ws + off);          off += (size_t)NCH * 4;
  off = (off + 255) & ~(size_t)255;
  int* packed = (int*)(ws + off);

  u16* Wmlp   = tab + 49152;
  u16* W1p    = tab + 57344;

  hipMemsetAsync(deg2, 0, (size_t)M * 8, stream);     // zero deg2 + cur2 (adjacent)

  const int HB = (E + 255) / 256;
  const int PB2 = 40;                                  // prep blocks (Wmlp/W1p only)
  k_fuse_hist_prep<<<NB + HB + PB2, 256, 0, stream>>>(
      des, nump, catp, desW, desB, numW, numB, catW, catB,
      dg, dbe, dm, dv, ng, nbe, nm, nv, cg, cbe, cm, cv,
      x16, N, NB, ei, et, E, HB, deg2, rgcnW, W1, tab);

  k_scanA<<<NCH, 256, 0, stream>>>(deg2, psum, M);
  k_scanB<<<1, 256, 0, stream>>>(psum, poff, NCH);
  k_scanC<<<NCH, 256, 0, stream>>>(deg2, poff, offs2, M, E);

  k_place<<<(E + 255) / 256, 256, 0, stream>>>(ei, et, E, offs2, cur2, packed);
  k_agg<<<2048, 256, 0, stream>>>(x16, offs2, packed, agg, N);
  k_mlp<<<(N + 63) / 64, 256, 0, stream>>>(agg, Wmlp, W1p, b1, W2, b2, (float2*)d_out, N);
}